// Round 1
// baseline (21639.626 us; speedup 1.0000x reference)
//
#include <hip/hip_runtime.h>

#define N_NODE 200000
#define FEAT 128
#define ALPHA 0.1f

// ---------------------------------------------------------------------------
// Scatter SpMM: for each edge e: dst[didx[e]] += vals[e] * src[sidx[e]]
// One wave (64 lanes) per edge; 2 floats per lane (128 features).
// ---------------------------------------------------------------------------
__global__ __launch_bounds__(256) void spmm_scatter(
        const float* __restrict__ src, float* __restrict__ dst,
        const int* __restrict__ sidx, const int* __restrict__ didx,
        const float* __restrict__ vals, int nedge) {
    int wid  = (int)((blockIdx.x * 256u + threadIdx.x) >> 6);
    int lane = threadIdx.x & 63;
    if (wid >= nedge) return;
    int s   = sidx[wid];
    int d   = didx[wid];
    float v = vals[wid];
    const float2* srow = (const float2*)(src + (size_t)s * FEAT);
    float*        drow = dst + (size_t)d * FEAT;
    float2 x = srow[lane];
    atomicAdd(drow + lane * 2,     v * x.x);
    atomicAdd(drow + lane * 2 + 1, v * x.y);
}

// ---------------------------------------------------------------------------
// C = act(A @ W + bias), A: Mx128, W: 128x128 (row-major [k][n]).
// Block: 256 threads (16 col-groups x 16 row-groups), tile 64 rows x 128 cols.
// Each thread: 4 rows x 8 cols. W staged in LDS (64 KB).
// act: leaky-relu (alpha=0.1)
// ---------------------------------------------------------------------------
__global__ __launch_bounds__(256) void gemm_leaky(
        const float* __restrict__ A, const float* __restrict__ W,
        const float* __restrict__ bias, float* __restrict__ C, int M) {
    __shared__ float Ws[FEAT * FEAT];
    {
        const float4* Wv = (const float4*)W;
        float4* Wsv = (float4*)Ws;
#pragma unroll
        for (int i = 0; i < 16; ++i)
            Wsv[threadIdx.x + i * 256] = Wv[threadIdx.x + i * 256];
    }
    __syncthreads();

    int tx = threadIdx.x & 15;   // col group: cols tx*8 .. tx*8+7
    int ty = threadIdx.x >> 4;   // row group: rows ty*4 ..
    long row0 = (long)blockIdx.x * 64 + ty * 4;
    if (row0 >= M) return;

    float acc[4][8] = {};
    const float* a0 = A + row0 * FEAT;

    for (int k4 = 0; k4 < FEAT; k4 += 4) {
        float4 a[4];
#pragma unroll
        for (int r = 0; r < 4; ++r)
            a[r] = *(const float4*)(a0 + (size_t)r * FEAT + k4);
#pragma unroll
        for (int kk = 0; kk < 4; ++kk) {
            float4 w0 = *(const float4*)(Ws + (k4 + kk) * FEAT + tx * 8);
            float4 w1 = *(const float4*)(Ws + (k4 + kk) * FEAT + tx * 8 + 4);
#pragma unroll
            for (int r = 0; r < 4; ++r) {
                float av = (&a[r].x)[kk];
                acc[r][0] = fmaf(av, w0.x, acc[r][0]);
                acc[r][1] = fmaf(av, w0.y, acc[r][1]);
                acc[r][2] = fmaf(av, w0.z, acc[r][2]);
                acc[r][3] = fmaf(av, w0.w, acc[r][3]);
                acc[r][4] = fmaf(av, w1.x, acc[r][4]);
                acc[r][5] = fmaf(av, w1.y, acc[r][5]);
                acc[r][6] = fmaf(av, w1.z, acc[r][6]);
                acc[r][7] = fmaf(av, w1.w, acc[r][7]);
            }
        }
    }

    float b0[8];
#pragma unroll
    for (int i = 0; i < 8; ++i) b0[i] = bias[tx * 8 + i];
#pragma unroll
    for (int r = 0; r < 4; ++r) {
        float o[8];
#pragma unroll
        for (int i = 0; i < 8; ++i) {
            float v = acc[r][i] + b0[i];
            o[i] = (v >= 0.f) ? v : ALPHA * v;
        }
        float* cp = C + (row0 + r) * FEAT + tx * 8;
        *(float4*)cp       = make_float4(o[0], o[1], o[2], o[3]);
        *(float4*)(cp + 4) = make_float4(o[4], o[5], o[6], o[7]);
    }
}

// ---------------------------------------------------------------------------
// C = relu(A @ W[0:128] + F @ W[128:256] + bias), W: 256x128.
// Same tiling; two K-phases re-staging LDS between them.
// ---------------------------------------------------------------------------
__global__ __launch_bounds__(256) void gemm_concat_relu(
        const float* __restrict__ A, const float* __restrict__ F,
        const float* __restrict__ W, const float* __restrict__ bias,
        float* __restrict__ C, int M) {
    __shared__ float Ws[FEAT * FEAT];
    int tx = threadIdx.x & 15;
    int ty = threadIdx.x >> 4;
    long row0 = (long)blockIdx.x * 64 + ty * 4;
    float acc[4][8] = {};

    for (int half = 0; half < 2; ++half) {
        __syncthreads();  // protect Ws readers from previous phase
        {
            const float4* Wv = (const float4*)(W + (size_t)half * FEAT * FEAT);
            float4* Wsv = (float4*)Ws;
#pragma unroll
            for (int i = 0; i < 16; ++i)
                Wsv[threadIdx.x + i * 256] = Wv[threadIdx.x + i * 256];
        }
        __syncthreads();

        const float* base = (half == 0 ? A : F);
        const float* a0 = base + row0 * FEAT;
        for (int k4 = 0; k4 < FEAT; k4 += 4) {
            float4 a[4];
#pragma unroll
            for (int r = 0; r < 4; ++r)
                a[r] = *(const float4*)(a0 + (size_t)r * FEAT + k4);
#pragma unroll
            for (int kk = 0; kk < 4; ++kk) {
                float4 w0 = *(const float4*)(Ws + (k4 + kk) * FEAT + tx * 8);
                float4 w1 = *(const float4*)(Ws + (k4 + kk) * FEAT + tx * 8 + 4);
#pragma unroll
                for (int r = 0; r < 4; ++r) {
                    float av = (&a[r].x)[kk];
                    acc[r][0] = fmaf(av, w0.x, acc[r][0]);
                    acc[r][1] = fmaf(av, w0.y, acc[r][1]);
                    acc[r][2] = fmaf(av, w0.z, acc[r][2]);
                    acc[r][3] = fmaf(av, w0.w, acc[r][3]);
                    acc[r][4] = fmaf(av, w1.x, acc[r][4]);
                    acc[r][5] = fmaf(av, w1.y, acc[r][5]);
                    acc[r][6] = fmaf(av, w1.z, acc[r][6]);
                    acc[r][7] = fmaf(av, w1.w, acc[r][7]);
                }
            }
        }
    }

    float b0[8];
#pragma unroll
    for (int i = 0; i < 8; ++i) b0[i] = bias[tx * 8 + i];
#pragma unroll
    for (int r = 0; r < 4; ++r) {
        float o[8];
#pragma unroll
        for (int i = 0; i < 8; ++i) {
            float v = acc[r][i] + b0[i];
            o[i] = (v >= 0.f) ? v : 0.f;
        }
        float* cp = C + (row0 + r) * FEAT + tx * 8;
        *(float4*)cp       = make_float4(o[0], o[1], o[2], o[3]);
        *(float4*)(cp + 4) = make_float4(o[4], o[5], o[6], o[7]);
    }
}

// ---------------------------------------------------------------------------
extern "C" void kernel_launch(void* const* d_in, const int* in_sizes, int n_in,
                              void* d_out, int out_size, void* d_ws, size_t ws_size,
                              hipStream_t stream) {
    const float* ufea    = (const float*)d_in[0];
    const float* vfea    = (const float*)d_in[1];
    const int*   uv_rows = (const int*)d_in[2];
    const int*   uv_cols = (const int*)d_in[3];
    const float* uv_vals = (const float*)d_in[4];
    const float* vu_vals = (const float*)d_in[5];
    const float* W1 = (const float*)d_in[6];
    const float* b1 = (const float*)d_in[7];
    const float* W2 = (const float*)d_in[8];
    const float* b2 = (const float*)d_in[9];
    const float* W3 = (const float*)d_in[10];
    const float* b3 = (const float*)d_in[11];
    const float* W4 = (const float*)d_in[12];
    const float* b4 = (const float*)d_in[13];
    const float* Wu = (const float*)d_in[14];
    const float* bu = (const float*)d_in[15];
    const float* Wi = (const float*)d_in[16];
    const float* bi = (const float*)d_in[17];

    float* out_user = (float*)d_out;
    float* out_item = out_user + (size_t)N_NODE * FEAT;

    size_t bufElems = (size_t)N_NODE * FEAT;          // 25.6M
    size_t bufBytes = bufElems * sizeof(float);       // 102.4 MB
    float* R  = (float*)d_ws;          // scatter target (reused 4x)
    float* B1 = R  + bufElems;         // A1 (user_ho item-side), then U3
    float* B2 = B1 + bufElems;         // A2 (item_ho user-side), then I4

    int nedge = in_sizes[2];
    dim3 sblk(256), sgrid((unsigned)((nedge + 3) / 4));
    dim3 gblk(256), ggrid((unsigned)(N_NODE / 64));   // 3125, exact

    // gc1: R1 = spmm_u2i(vu_vals, ufea)  [src=rows -> dst=cols]; A1 = leaky(R1@W1+b1)
    hipMemsetAsync(R, 0, bufBytes, stream);
    spmm_scatter<<<sgrid, sblk, 0, stream>>>(ufea, R, uv_rows, uv_cols, vu_vals, nedge);
    gemm_leaky<<<ggrid, gblk, 0, stream>>>(R, W1, b1, B1, N_NODE);

    // gc2: R2 = spmm_i2u(uv_vals, vfea)  [src=cols -> dst=rows]; A2 = leaky(R2@W2+b2)
    hipMemsetAsync(R, 0, bufBytes, stream);
    spmm_scatter<<<sgrid, sblk, 0, stream>>>(vfea, R, uv_cols, uv_rows, uv_vals, nedge);
    gemm_leaky<<<ggrid, gblk, 0, stream>>>(R, W2, b2, B2, N_NODE);

    // gc3: R3 = spmm_i2u(uv_vals, A1); U3 = leaky(R3@W3+b3)  -> overwrite B1
    hipMemsetAsync(R, 0, bufBytes, stream);
    spmm_scatter<<<sgrid, sblk, 0, stream>>>(B1, R, uv_cols, uv_rows, uv_vals, nedge);
    gemm_leaky<<<ggrid, gblk, 0, stream>>>(R, W3, b3, B1, N_NODE);

    // gc4: R4 = spmm_u2i(vu_vals, A2); I4 = leaky(R4@W4+b4)  -> overwrite B2
    hipMemsetAsync(R, 0, bufBytes, stream);
    spmm_scatter<<<sgrid, sblk, 0, stream>>>(B2, R, uv_rows, uv_cols, vu_vals, nedge);
    gemm_leaky<<<ggrid, gblk, 0, stream>>>(R, W4, b4, B2, N_NODE);

    // finals: user = relu([U3|ufea]@Wu + bu); item = relu([I4|vfea]@Wi + bi)
    gemm_concat_relu<<<ggrid, gblk, 0, stream>>>(B1, ufea, Wu, bu, out_user, N_NODE);
    gemm_concat_relu<<<ggrid, gblk, 0, stream>>>(B2, vfea, Wi, bi, out_item, N_NODE);
}

// Round 2
// 4112.912 us; speedup vs baseline: 5.2614x; 5.2614x over previous
//
#include <hip/hip_runtime.h>

#define N_NODE 200000
#define FEAT 128
#define ALPHA 0.1f

// ---------------------------------------------------------------------------
// CSR build: histogram -> scan -> placement
// ---------------------------------------------------------------------------
__global__ __launch_bounds__(256) void edge_hist(
        const int* __restrict__ didx, int* __restrict__ cnt, int nedge) {
    int i = blockIdx.x * 256 + threadIdx.x;
    if (i < nedge) atomicAdd(&cnt[didx[i]], 1);
}

// per-block sums of 256 counts
__global__ __launch_bounds__(256) void scan_block_sums(
        const int* __restrict__ cnt, int* __restrict__ bsum, int n) {
    __shared__ int s[256];
    int i = blockIdx.x * 256 + threadIdx.x;
    s[threadIdx.x] = (i < n) ? cnt[i] : 0;
    __syncthreads();
    for (int o = 128; o > 0; o >>= 1) {
        if (threadIdx.x < o) s[threadIdx.x] += s[threadIdx.x + o];
        __syncthreads();
    }
    if (threadIdx.x == 0) bsum[blockIdx.x] = s[0];
}

// single block: exclusive scan of block sums (nb <= 1024); also rp[N]=nedge
__global__ __launch_bounds__(1024) void scan_top(
        int* bsum, int nb, int* __restrict__ rp, int nedge) {
    __shared__ int s[1024];
    int t = threadIdx.x;
    int v = (t < nb) ? bsum[t] : 0;
    s[t] = v;
    __syncthreads();
    for (int o = 1; o < 1024; o <<= 1) {
        int add = (t >= o) ? s[t - o] : 0;
        __syncthreads();
        s[t] += add;
        __syncthreads();
    }
    if (t < nb) bsum[t] = s[t] - v;   // exclusive
    if (t == 0) rp[N_NODE] = nedge;
}

// per-block exclusive scan + block offset -> row_ptr
__global__ __launch_bounds__(256) void scan_final(
        const int* __restrict__ cnt, const int* __restrict__ bsum,
        int* __restrict__ rp, int n) {
    __shared__ int s[256];
    int i = blockIdx.x * 256 + threadIdx.x;
    int v = (i < n) ? cnt[i] : 0;
    s[threadIdx.x] = v;
    __syncthreads();
    for (int o = 1; o < 256; o <<= 1) {
        int add = (threadIdx.x >= o) ? s[threadIdx.x - o] : 0;
        __syncthreads();
        s[threadIdx.x] += add;
        __syncthreads();
    }
    if (i < n) rp[i] = bsum[blockIdx.x] + s[threadIdx.x] - v;
}

__global__ __launch_bounds__(256) void edge_place(
        const int* __restrict__ sidx, const int* __restrict__ didx,
        const float* __restrict__ vals, const int* __restrict__ rp,
        int* __restrict__ cur, int* __restrict__ psrc, float* __restrict__ pval,
        int nedge) {
    int i = blockIdx.x * 256 + threadIdx.x;
    if (i >= nedge) return;
    int d = didx[i];
    int pos = rp[d] + atomicAdd(&cur[d], 1);
    psrc[pos] = sidx[i];
    pval[pos] = vals[i];
}

// ---------------------------------------------------------------------------
// Gather SpMM: one wave per dst node; acc 128 feats in regs (float2/lane).
// ---------------------------------------------------------------------------
__global__ __launch_bounds__(256) void spmm_gather(
        const float* __restrict__ src, float* __restrict__ dst,
        const int* __restrict__ rp, const int* __restrict__ psrc,
        const float* __restrict__ pval, int ndst) {
    int wid  = (int)((blockIdx.x * 256u + threadIdx.x) >> 6);
    int lane = threadIdx.x & 63;
    if (wid >= ndst) return;
    int e0 = rp[wid], e1 = rp[wid + 1];
    float2 acc = make_float2(0.f, 0.f);
    int e = e0;
    for (; e + 1 < e1; e += 2) {
        int   s0 = psrc[e],     s1 = psrc[e + 1];
        float v0 = pval[e],     v1 = pval[e + 1];
        float2 x0 = *(const float2*)(src + (size_t)s0 * FEAT + lane * 2);
        float2 x1 = *(const float2*)(src + (size_t)s1 * FEAT + lane * 2);
        acc.x = fmaf(v0, x0.x, acc.x);
        acc.y = fmaf(v0, x0.y, acc.y);
        acc.x = fmaf(v1, x1.x, acc.x);
        acc.y = fmaf(v1, x1.y, acc.y);
    }
    if (e < e1) {
        int s0 = psrc[e];
        float v0 = pval[e];
        float2 x0 = *(const float2*)(src + (size_t)s0 * FEAT + lane * 2);
        acc.x = fmaf(v0, x0.x, acc.x);
        acc.y = fmaf(v0, x0.y, acc.y);
    }
    *(float2*)(dst + (size_t)wid * FEAT + lane * 2) = acc;
}

// ---------------------------------------------------------------------------
// C = leaky(A @ W + bias) IN PLACE (A == C allowed: each wave reads only the
// 16 rows it later writes; no cross-wave row sharing).
// ---------------------------------------------------------------------------
__global__ __launch_bounds__(256) void gemm_leaky(
        const float* A, const float* __restrict__ W,
        const float* __restrict__ bias, float* C, int M) {
    __shared__ float Ws[FEAT * FEAT];
    {
        const float4* Wv = (const float4*)W;
        float4* Wsv = (float4*)Ws;
#pragma unroll
        for (int i = 0; i < 16; ++i)
            Wsv[threadIdx.x + i * 256] = Wv[threadIdx.x + i * 256];
    }
    __syncthreads();

    int tx = threadIdx.x & 15;
    int ty = threadIdx.x >> 4;
    long row0 = (long)blockIdx.x * 64 + ty * 4;
    if (row0 >= M) return;

    float acc[4][8] = {};
    const float* a0 = A + row0 * FEAT;

    for (int k4 = 0; k4 < FEAT; k4 += 4) {
        float4 a[4];
#pragma unroll
        for (int r = 0; r < 4; ++r)
            a[r] = *(const float4*)(a0 + (size_t)r * FEAT + k4);
#pragma unroll
        for (int kk = 0; kk < 4; ++kk) {
            float4 w0 = *(const float4*)(Ws + (k4 + kk) * FEAT + tx * 8);
            float4 w1 = *(const float4*)(Ws + (k4 + kk) * FEAT + tx * 8 + 4);
#pragma unroll
            for (int r = 0; r < 4; ++r) {
                float av = (&a[r].x)[kk];
                acc[r][0] = fmaf(av, w0.x, acc[r][0]);
                acc[r][1] = fmaf(av, w0.y, acc[r][1]);
                acc[r][2] = fmaf(av, w0.z, acc[r][2]);
                acc[r][3] = fmaf(av, w0.w, acc[r][3]);
                acc[r][4] = fmaf(av, w1.x, acc[r][4]);
                acc[r][5] = fmaf(av, w1.y, acc[r][5]);
                acc[r][6] = fmaf(av, w1.z, acc[r][6]);
                acc[r][7] = fmaf(av, w1.w, acc[r][7]);
            }
        }
    }

    float b0[8];
#pragma unroll
    for (int i = 0; i < 8; ++i) b0[i] = bias[tx * 8 + i];
#pragma unroll
    for (int r = 0; r < 4; ++r) {
        float o[8];
#pragma unroll
        for (int i = 0; i < 8; ++i) {
            float v = acc[r][i] + b0[i];
            o[i] = (v >= 0.f) ? v : ALPHA * v;
        }
        float* cp = C + (row0 + r) * FEAT + tx * 8;
        *(float4*)cp       = make_float4(o[0], o[1], o[2], o[3]);
        *(float4*)(cp + 4) = make_float4(o[4], o[5], o[6], o[7]);
    }
}

// ---------------------------------------------------------------------------
// C = relu(A @ W[0:128] + F @ W[128:256] + bias), W: 256x128.
// ---------------------------------------------------------------------------
__global__ __launch_bounds__(256) void gemm_concat_relu(
        const float* __restrict__ A, const float* __restrict__ F,
        const float* __restrict__ W, const float* __restrict__ bias,
        float* __restrict__ C, int M) {
    __shared__ float Ws[FEAT * FEAT];
    int tx = threadIdx.x & 15;
    int ty = threadIdx.x >> 4;
    long row0 = (long)blockIdx.x * 64 + ty * 4;
    float acc[4][8] = {};

    for (int half = 0; half < 2; ++half) {
        __syncthreads();
        {
            const float4* Wv = (const float4*)(W + (size_t)half * FEAT * FEAT);
            float4* Wsv = (float4*)Ws;
#pragma unroll
            for (int i = 0; i < 16; ++i)
                Wsv[threadIdx.x + i * 256] = Wv[threadIdx.x + i * 256];
        }
        __syncthreads();

        const float* base = (half == 0 ? A : F);
        const float* a0 = base + row0 * FEAT;
        for (int k4 = 0; k4 < FEAT; k4 += 4) {
            float4 a[4];
#pragma unroll
            for (int r = 0; r < 4; ++r)
                a[r] = *(const float4*)(a0 + (size_t)r * FEAT + k4);
#pragma unroll
            for (int kk = 0; kk < 4; ++kk) {
                float4 w0 = *(const float4*)(Ws + (k4 + kk) * FEAT + tx * 8);
                float4 w1 = *(const float4*)(Ws + (k4 + kk) * FEAT + tx * 8 + 4);
#pragma unroll
                for (int r = 0; r < 4; ++r) {
                    float av = (&a[r].x)[kk];
                    acc[r][0] = fmaf(av, w0.x, acc[r][0]);
                    acc[r][1] = fmaf(av, w0.y, acc[r][1]);
                    acc[r][2] = fmaf(av, w0.z, acc[r][2]);
                    acc[r][3] = fmaf(av, w0.w, acc[r][3]);
                    acc[r][4] = fmaf(av, w1.x, acc[r][4]);
                    acc[r][5] = fmaf(av, w1.y, acc[r][5]);
                    acc[r][6] = fmaf(av, w1.z, acc[r][6]);
                    acc[r][7] = fmaf(av, w1.w, acc[r][7]);
                }
            }
        }
    }

    float b0[8];
#pragma unroll
    for (int i = 0; i < 8; ++i) b0[i] = bias[tx * 8 + i];
#pragma unroll
    for (int r = 0; r < 4; ++r) {
        float o[8];
#pragma unroll
        for (int i = 0; i < 8; ++i) {
            float v = acc[r][i] + b0[i];
            o[i] = (v >= 0.f) ? v : 0.f;
        }
        float* cp = C + (row0 + r) * FEAT + tx * 8;
        *(float4*)cp       = make_float4(o[0], o[1], o[2], o[3]);
        *(float4*)(cp + 4) = make_float4(o[4], o[5], o[6], o[7]);
    }
}

// ---------------------------------------------------------------------------
extern "C" void kernel_launch(void* const* d_in, const int* in_sizes, int n_in,
                              void* d_out, int out_size, void* d_ws, size_t ws_size,
                              hipStream_t stream) {
    const float* ufea    = (const float*)d_in[0];
    const float* vfea    = (const float*)d_in[1];
    const int*   uv_rows = (const int*)d_in[2];
    const int*   uv_cols = (const int*)d_in[3];
    const float* uv_vals = (const float*)d_in[4];
    const float* vu_vals = (const float*)d_in[5];
    const float* W1 = (const float*)d_in[6];
    const float* b1 = (const float*)d_in[7];
    const float* W2 = (const float*)d_in[8];
    const float* b2 = (const float*)d_in[9];
    const float* W3 = (const float*)d_in[10];
    const float* b3 = (const float*)d_in[11];
    const float* W4 = (const float*)d_in[12];
    const float* b4 = (const float*)d_in[13];
    const float* Wu = (const float*)d_in[14];
    const float* bu = (const float*)d_in[15];
    const float* Wi = (const float*)d_in[16];
    const float* bi = (const float*)d_in[17];

    float* out_user = (float*)d_out;
    float* out_item = out_user + (size_t)N_NODE * FEAT;

    int nedge = in_sizes[2];
    size_t nfe = (size_t)N_NODE * FEAT;      // 25.6M floats

    float* T1 = (float*)d_ws;
    float* T2 = T1 + nfe;
    float* T3 = T2 + nfe;
    int* rpA   = (int*)(T3 + nfe);           // N_NODE+1
    int* rpB   = rpA + (N_NODE + 64);
    int* cnt   = rpB + (N_NODE + 64);        // histogram / cursor
    int* bsum  = cnt + N_NODE;               // block sums (<=1024)
    int* psrcA = bsum + 1024;
    float* pvalA = (float*)(psrcA + nedge);
    int* psrcB   = (int*)(pvalA + nedge);
    float* pvalB = (float*)(psrcB + nedge);

    int eb = (nedge + 255) / 256;            // edge-grid blocks
    int nb = (N_NODE + 255) / 256;           // node-grid blocks (782)
    dim3 b256(256);
    dim3 ggrid((unsigned)(N_NODE / 64));     // 3125, exact
    dim3 sgrid((unsigned)((N_NODE * 64 + 255) / 256)); // wave per dst: 50000

    // ---- CSR A: dst = uv_cols (items), src = uv_rows, val = vu_vals ----
    hipMemsetAsync(cnt, 0, N_NODE * sizeof(int), stream);
    edge_hist<<<eb, b256, 0, stream>>>(uv_cols, cnt, nedge);
    scan_block_sums<<<nb, b256, 0, stream>>>(cnt, bsum, N_NODE);
    scan_top<<<1, 1024, 0, stream>>>(bsum, nb, rpA, nedge);
    scan_final<<<nb, b256, 0, stream>>>(cnt, bsum, rpA, N_NODE);
    hipMemsetAsync(cnt, 0, N_NODE * sizeof(int), stream);
    edge_place<<<eb, b256, 0, stream>>>(uv_rows, uv_cols, vu_vals, rpA, cnt,
                                        psrcA, pvalA, nedge);

    // ---- CSR B: dst = uv_rows (users), src = uv_cols, val = uv_vals ----
    hipMemsetAsync(cnt, 0, N_NODE * sizeof(int), stream);
    edge_hist<<<eb, b256, 0, stream>>>(uv_rows, cnt, nedge);
    scan_block_sums<<<nb, b256, 0, stream>>>(cnt, bsum, N_NODE);
    scan_top<<<1, 1024, 0, stream>>>(bsum, nb, rpB, nedge);
    scan_final<<<nb, b256, 0, stream>>>(cnt, bsum, rpB, N_NODE);
    hipMemsetAsync(cnt, 0, N_NODE * sizeof(int), stream);
    edge_place<<<eb, b256, 0, stream>>>(uv_cols, uv_rows, uv_vals, rpB, cnt,
                                        psrcB, pvalB, nedge);

    // gc1: T1 = leaky( (VU @ ufea) @ W1 + b1 )   [CSR A]
    spmm_gather<<<sgrid, b256, 0, stream>>>(ufea, T1, rpA, psrcA, pvalA, N_NODE);
    gemm_leaky<<<ggrid, b256, 0, stream>>>(T1, W1, b1, T1, N_NODE);

    // gc2: T2 = leaky( (UV @ vfea) @ W2 + b2 )   [CSR B]
    spmm_gather<<<sgrid, b256, 0, stream>>>(vfea, T2, rpB, psrcB, pvalB, N_NODE);
    gemm_leaky<<<ggrid, b256, 0, stream>>>(T2, W2, b2, T2, N_NODE);

    // gc3: T3 = leaky( (UV @ T1) @ W3 + b3 )     [CSR B]
    spmm_gather<<<sgrid, b256, 0, stream>>>(T1, T3, rpB, psrcB, pvalB, N_NODE);
    gemm_leaky<<<ggrid, b256, 0, stream>>>(T3, W3, b3, T3, N_NODE);

    // gc4: T1 = leaky( (VU @ T2) @ W4 + b4 )     [CSR A]
    spmm_gather<<<sgrid, b256, 0, stream>>>(T2, T1, rpA, psrcA, pvalA, N_NODE);
    gemm_leaky<<<ggrid, b256, 0, stream>>>(T1, W4, b4, T1, N_NODE);

    // finals
    gemm_concat_relu<<<ggrid, b256, 0, stream>>>(T3, ufea, Wu, bu, out_user, N_NODE);
    gemm_concat_relu<<<ggrid, b256, 0, stream>>>(T1, vfea, Wi, bi, out_item, N_NODE);
}

// Round 3
// 3843.588 us; speedup vs baseline: 5.6301x; 1.0701x over previous
//
#include <hip/hip_runtime.h>

#define N_NODE 200000
#define FEAT 128
#define ALPHA 0.1f

// ---------------------------------------------------------------------------
// CSR build (both CSRs in one pass over the edge list)
// CSR A: dst = uv_cols (items),  src = uv_rows, val = vu_vals
// CSR B: dst = uv_rows (users),  src = uv_cols, val = uv_vals
// ---------------------------------------------------------------------------
__global__ __launch_bounds__(256) void edge_hist_dual(
        const int* __restrict__ rows, const int* __restrict__ cols,
        int* __restrict__ cntA, int* __restrict__ cntB, int nedge) {
    int i = blockIdx.x * 256 + threadIdx.x;
    if (i >= nedge) return;
    atomicAdd(&cntA[cols[i]], 1);
    atomicAdd(&cntB[rows[i]], 1);
}

__global__ __launch_bounds__(256) void scan_block_sums(
        const int* __restrict__ cnt, int* __restrict__ bsum, int n) {
    __shared__ int s[256];
    int i = blockIdx.x * 256 + threadIdx.x;
    s[threadIdx.x] = (i < n) ? cnt[i] : 0;
    __syncthreads();
    for (int o = 128; o > 0; o >>= 1) {
        if (threadIdx.x < o) s[threadIdx.x] += s[threadIdx.x + o];
        __syncthreads();
    }
    if (threadIdx.x == 0) bsum[blockIdx.x] = s[0];
}

__global__ __launch_bounds__(1024) void scan_top(
        int* bsum, int nb, int* __restrict__ rp, int nedge) {
    __shared__ int s[1024];
    int t = threadIdx.x;
    int v = (t < nb) ? bsum[t] : 0;
    s[t] = v;
    __syncthreads();
    for (int o = 1; o < 1024; o <<= 1) {
        int add = (t >= o) ? s[t - o] : 0;
        __syncthreads();
        s[t] += add;
        __syncthreads();
    }
    if (t < nb) bsum[t] = s[t] - v;   // exclusive
    if (t == 0) rp[N_NODE] = nedge;
}

__global__ __launch_bounds__(256) void scan_final(
        const int* __restrict__ cnt, const int* __restrict__ bsum,
        int* __restrict__ rp, int n) {
    __shared__ int s[256];
    int i = blockIdx.x * 256 + threadIdx.x;
    int v = (i < n) ? cnt[i] : 0;
    s[threadIdx.x] = v;
    __syncthreads();
    for (int o = 1; o < 256; o <<= 1) {
        int add = (threadIdx.x >= o) ? s[threadIdx.x - o] : 0;
        __syncthreads();
        s[threadIdx.x] += add;
        __syncthreads();
    }
    if (i < n) rp[i] = bsum[blockIdx.x] + s[threadIdx.x] - v;
}

__global__ __launch_bounds__(256) void edge_place_dual(
        const int* __restrict__ rows, const int* __restrict__ cols,
        const float* __restrict__ uvv, const float* __restrict__ vuv,
        const int* __restrict__ rpA, int* __restrict__ curA, int2* __restrict__ eA,
        const int* __restrict__ rpB, int* __restrict__ curB, int2* __restrict__ eB,
        int nedge) {
    int i = blockIdx.x * 256 + threadIdx.x;
    if (i >= nedge) return;
    int r = rows[i], c = cols[i];
    int pa = rpA[c] + atomicAdd(&curA[c], 1);
    eA[pa] = make_int2(r, __float_as_int(vuv[i]));
    int pb = rpB[r] + atomicAdd(&curB[r], 1);
    eB[pb] = make_int2(c, __float_as_int(uvv[i]));
}

// ---------------------------------------------------------------------------
// Gather SpMM with fused epilogue: dst[n] = leaky(sum_e val*src[srcidx] + bias)
// One wave per dst node; float2/lane; 4-edge unroll.
// ---------------------------------------------------------------------------
__global__ __launch_bounds__(256) void spmm_gather_act(
        const float* __restrict__ src, float* __restrict__ dst,
        const int* __restrict__ rp, const int2* __restrict__ edges,
        const float* __restrict__ bias, int ndst) {
    int wid = __builtin_amdgcn_readfirstlane(
        (int)((blockIdx.x * 256u + threadIdx.x) >> 6));
    int lane = threadIdx.x & 63;
    if (wid >= ndst) return;
    float2 b = *(const float2*)(bias + lane * 2);
    int e0 = rp[wid], e1 = rp[wid + 1];
    float2 acc = make_float2(0.f, 0.f);
    int e = e0;
    for (; e + 4 <= e1; e += 4) {
        int2 ev0 = edges[e],     ev1 = edges[e + 1];
        int2 ev2 = edges[e + 2], ev3 = edges[e + 3];
        float2 x0 = *(const float2*)(src + (size_t)ev0.x * FEAT + lane * 2);
        float2 x1 = *(const float2*)(src + (size_t)ev1.x * FEAT + lane * 2);
        float2 x2 = *(const float2*)(src + (size_t)ev2.x * FEAT + lane * 2);
        float2 x3 = *(const float2*)(src + (size_t)ev3.x * FEAT + lane * 2);
        float v0 = __int_as_float(ev0.y), v1 = __int_as_float(ev1.y);
        float v2 = __int_as_float(ev2.y), v3 = __int_as_float(ev3.y);
        acc.x = fmaf(v0, x0.x, acc.x);  acc.y = fmaf(v0, x0.y, acc.y);
        acc.x = fmaf(v1, x1.x, acc.x);  acc.y = fmaf(v1, x1.y, acc.y);
        acc.x = fmaf(v2, x2.x, acc.x);  acc.y = fmaf(v2, x2.y, acc.y);
        acc.x = fmaf(v3, x3.x, acc.x);  acc.y = fmaf(v3, x3.y, acc.y);
    }
    for (; e < e1; ++e) {
        int2 ev = edges[e];
        float2 x = *(const float2*)(src + (size_t)ev.x * FEAT + lane * 2);
        float v = __int_as_float(ev.y);
        acc.x = fmaf(v, x.x, acc.x);  acc.y = fmaf(v, x.y, acc.y);
    }
    float ox = acc.x + b.x;
    float oy = acc.y + b.y;
    ox = (ox >= 0.f) ? ox : ALPHA * ox;
    oy = (oy >= 0.f) ? oy : ALPHA * oy;
    *(float2*)(dst + (size_t)wid * FEAT + lane * 2) = make_float2(ox, oy);
}

// ---------------------------------------------------------------------------
// C = A @ W  (A: Mx128, W: 128x128 row-major [k][n]); no bias/activation.
// ---------------------------------------------------------------------------
__global__ __launch_bounds__(256) void gemm_plain(
        const float* __restrict__ A, const float* __restrict__ W,
        float* __restrict__ C, int M) {
    __shared__ float Ws[FEAT * FEAT];
    {
        const float4* Wv = (const float4*)W;
        float4* Wsv = (float4*)Ws;
#pragma unroll
        for (int i = 0; i < 16; ++i)
            Wsv[threadIdx.x + i * 256] = Wv[threadIdx.x + i * 256];
    }
    __syncthreads();

    int tx = threadIdx.x & 15;
    int ty = threadIdx.x >> 4;
    long row0 = (long)blockIdx.x * 64 + ty * 4;
    if (row0 >= M) return;

    float acc[4][8] = {};
    const float* a0 = A + row0 * FEAT;

    for (int k4 = 0; k4 < FEAT; k4 += 4) {
        float4 a[4];
#pragma unroll
        for (int r = 0; r < 4; ++r)
            a[r] = *(const float4*)(a0 + (size_t)r * FEAT + k4);
#pragma unroll
        for (int kk = 0; kk < 4; ++kk) {
            float4 w0 = *(const float4*)(Ws + (k4 + kk) * FEAT + tx * 8);
            float4 w1 = *(const float4*)(Ws + (k4 + kk) * FEAT + tx * 8 + 4);
#pragma unroll
            for (int r = 0; r < 4; ++r) {
                float av = (&a[r].x)[kk];
                acc[r][0] = fmaf(av, w0.x, acc[r][0]);
                acc[r][1] = fmaf(av, w0.y, acc[r][1]);
                acc[r][2] = fmaf(av, w0.z, acc[r][2]);
                acc[r][3] = fmaf(av, w0.w, acc[r][3]);
                acc[r][4] = fmaf(av, w1.x, acc[r][4]);
                acc[r][5] = fmaf(av, w1.y, acc[r][5]);
                acc[r][6] = fmaf(av, w1.z, acc[r][6]);
                acc[r][7] = fmaf(av, w1.w, acc[r][7]);
            }
        }
    }

#pragma unroll
    for (int r = 0; r < 4; ++r) {
        float* cp = C + (row0 + r) * FEAT + tx * 8;
        *(float4*)cp       = make_float4(acc[r][0], acc[r][1], acc[r][2], acc[r][3]);
        *(float4*)(cp + 4) = make_float4(acc[r][4], acc[r][5], acc[r][6], acc[r][7]);
    }
}

// ---------------------------------------------------------------------------
// C = relu(A @ W[0:128] + F @ W[128:256] + bias), W: 256x128.
// ---------------------------------------------------------------------------
__global__ __launch_bounds__(256) void gemm_concat_relu(
        const float* __restrict__ A, const float* __restrict__ F,
        const float* __restrict__ W, const float* __restrict__ bias,
        float* __restrict__ C, int M) {
    __shared__ float Ws[FEAT * FEAT];
    int tx = threadIdx.x & 15;
    int ty = threadIdx.x >> 4;
    long row0 = (long)blockIdx.x * 64 + ty * 4;
    float acc[4][8] = {};

    for (int half = 0; half < 2; ++half) {
        __syncthreads();
        {
            const float4* Wv = (const float4*)(W + (size_t)half * FEAT * FEAT);
            float4* Wsv = (float4*)Ws;
#pragma unroll
            for (int i = 0; i < 16; ++i)
                Wsv[threadIdx.x + i * 256] = Wv[threadIdx.x + i * 256];
        }
        __syncthreads();

        const float* base = (half == 0 ? A : F);
        const float* a0 = base + row0 * FEAT;
        for (int k4 = 0; k4 < FEAT; k4 += 4) {
            float4 a[4];
#pragma unroll
            for (int r = 0; r < 4; ++r)
                a[r] = *(const float4*)(a0 + (size_t)r * FEAT + k4);
#pragma unroll
            for (int kk = 0; kk < 4; ++kk) {
                float4 w0 = *(const float4*)(Ws + (k4 + kk) * FEAT + tx * 8);
                float4 w1 = *(const float4*)(Ws + (k4 + kk) * FEAT + tx * 8 + 4);
#pragma unroll
                for (int r = 0; r < 4; ++r) {
                    float av = (&a[r].x)[kk];
                    acc[r][0] = fmaf(av, w0.x, acc[r][0]);
                    acc[r][1] = fmaf(av, w0.y, acc[r][1]);
                    acc[r][2] = fmaf(av, w0.z, acc[r][2]);
                    acc[r][3] = fmaf(av, w0.w, acc[r][3]);
                    acc[r][4] = fmaf(av, w1.x, acc[r][4]);
                    acc[r][5] = fmaf(av, w1.y, acc[r][5]);
                    acc[r][6] = fmaf(av, w1.z, acc[r][6]);
                    acc[r][7] = fmaf(av, w1.w, acc[r][7]);
                }
            }
        }
    }

    float b0[8];
#pragma unroll
    for (int i = 0; i < 8; ++i) b0[i] = bias[tx * 8 + i];
#pragma unroll
    for (int r = 0; r < 4; ++r) {
        float o[8];
#pragma unroll
        for (int i = 0; i < 8; ++i) {
            float v = acc[r][i] + b0[i];
            o[i] = (v >= 0.f) ? v : 0.f;
        }
        float* cp = C + (row0 + r) * FEAT + tx * 8;
        *(float4*)cp       = make_float4(o[0], o[1], o[2], o[3]);
        *(float4*)(cp + 4) = make_float4(o[4], o[5], o[6], o[7]);
    }
}

// ---------------------------------------------------------------------------
extern "C" void kernel_launch(void* const* d_in, const int* in_sizes, int n_in,
                              void* d_out, int out_size, void* d_ws, size_t ws_size,
                              hipStream_t stream) {
    const float* ufea    = (const float*)d_in[0];
    const float* vfea    = (const float*)d_in[1];
    const int*   uv_rows = (const int*)d_in[2];
    const int*   uv_cols = (const int*)d_in[3];
    const float* uv_vals = (const float*)d_in[4];
    const float* vu_vals = (const float*)d_in[5];
    const float* W1 = (const float*)d_in[6];
    const float* b1 = (const float*)d_in[7];
    const float* W2 = (const float*)d_in[8];
    const float* b2 = (const float*)d_in[9];
    const float* W3 = (const float*)d_in[10];
    const float* b3 = (const float*)d_in[11];
    const float* W4 = (const float*)d_in[12];
    const float* b4 = (const float*)d_in[13];
    const float* Wu = (const float*)d_in[14];
    const float* bu = (const float*)d_in[15];
    const float* Wi = (const float*)d_in[16];
    const float* bi = (const float*)d_in[17];

    float* out_user = (float*)d_out;
    float* out_item = out_user + (size_t)N_NODE * FEAT;

    int nedge = in_sizes[2];
    size_t nfe = (size_t)N_NODE * FEAT;      // 25.6M floats

    float* A = (float*)d_ws;                 // G buffer (transformed feats)
    float* B = A + nfe;
    float* C = B + nfe;
    int* rpA  = (int*)(C + nfe);             // N_NODE+1 (padded)
    int* rpB  = rpA + (N_NODE + 64);
    int* cnt  = rpB + (N_NODE + 64);         // 2*N_NODE: [cntA | cntB]
    int* cntA = cnt;
    int* cntB = cnt + N_NODE;
    int* bsum = cntB + N_NODE;               // <=1024
    int2* eA  = (int2*)(bsum + 1024);        // AoS {src, val_bits}
    int2* eB  = eA + nedge;

    int eb = (nedge + 255) / 256;
    int nb = (N_NODE + 255) / 256;           // 782
    dim3 b256(256);
    dim3 ggrid((unsigned)(N_NODE / 64));     // 3125
    dim3 sgrid((unsigned)(N_NODE / 4));      // 50000: wave per dst node

    // ---- dual CSR build ----
    hipMemsetAsync(cnt, 0, 2u * N_NODE * sizeof(int), stream);
    edge_hist_dual<<<eb, b256, 0, stream>>>(uv_rows, uv_cols, cntA, cntB, nedge);
    scan_block_sums<<<nb, b256, 0, stream>>>(cntA, bsum, N_NODE);
    scan_top<<<1, 1024, 0, stream>>>(bsum, nb, rpA, nedge);
    scan_final<<<nb, b256, 0, stream>>>(cntA, bsum, rpA, N_NODE);
    scan_block_sums<<<nb, b256, 0, stream>>>(cntB, bsum, N_NODE);
    scan_top<<<1, 1024, 0, stream>>>(bsum, nb, rpB, nedge);
    scan_final<<<nb, b256, 0, stream>>>(cntB, bsum, rpB, N_NODE);
    hipMemsetAsync(cnt, 0, 2u * N_NODE * sizeof(int), stream);
    edge_place_dual<<<eb, b256, 0, stream>>>(uv_rows, uv_cols, uv_vals, vu_vals,
                                             rpA, cntA, eA, rpB, cntB, eB, nedge);

    // gc1: G1 = ufea@W1 -> A;  T1 = leaky(gatherA(G1)+b1) -> B
    gemm_plain<<<ggrid, b256, 0, stream>>>(ufea, W1, A, N_NODE);
    spmm_gather_act<<<sgrid, b256, 0, stream>>>(A, B, rpA, eA, b1, N_NODE);

    // gc2: G2 = vfea@W2 -> A;  T2 = leaky(gatherB(G2)+b2) -> C
    gemm_plain<<<ggrid, b256, 0, stream>>>(vfea, W2, A, N_NODE);
    spmm_gather_act<<<sgrid, b256, 0, stream>>>(A, C, rpB, eB, b2, N_NODE);

    // gc3: G3 = T1@W3 -> A;    T3 = leaky(gatherB(G3)+b3) -> B (T1 dead)
    gemm_plain<<<ggrid, b256, 0, stream>>>(B, W3, A, N_NODE);
    spmm_gather_act<<<sgrid, b256, 0, stream>>>(A, B, rpB, eB, b3, N_NODE);

    // gc4: G4 = T2@W4 -> A;    T4 = leaky(gatherA(G4)+b4) -> C (T2 dead)
    gemm_plain<<<ggrid, b256, 0, stream>>>(C, W4, A, N_NODE);
    spmm_gather_act<<<sgrid, b256, 0, stream>>>(A, C, rpA, eA, b4, N_NODE);

    // finals
    gemm_concat_relu<<<ggrid, b256, 0, stream>>>(B, ufea, Wu, bu, out_user, N_NODE);
    gemm_concat_relu<<<ggrid, b256, 0, stream>>>(C, vfea, Wi, bi, out_item, N_NODE);
}

// Round 4
// 2998.851 us; speedup vs baseline: 7.2160x; 1.2817x over previous
//
#include <hip/hip_runtime.h>

#define N_NODE 200000
#define FEAT 128
#define ALPHA 0.1f

// ---------------------------------------------------------------------------
// bf16 pack/unpack helpers (RNE)
// ---------------------------------------------------------------------------
__device__ inline unsigned bf16pk(float a, float b) {
    unsigned ua = __float_as_uint(a); ua += ((ua >> 16) & 1u) + 0x7FFFu;
    unsigned ub = __float_as_uint(b); ub += ((ub >> 16) & 1u) + 0x7FFFu;
    return (ua >> 16) | (ub & 0xFFFF0000u);
}

// ---------------------------------------------------------------------------
// CSR build (both CSRs in one pass over the edge list)
// CSR A: dst = uv_cols (items),  src = uv_rows, val = vu_vals
// CSR B: dst = uv_rows (users),  src = uv_cols, val = uv_vals
// ---------------------------------------------------------------------------
__global__ __launch_bounds__(256) void edge_hist_dual(
        const int* __restrict__ rows, const int* __restrict__ cols,
        int* __restrict__ cntA, int* __restrict__ cntB, int nedge) {
    int i = blockIdx.x * 256 + threadIdx.x;
    if (i >= nedge) return;
    atomicAdd(&cntA[cols[i]], 1);
    atomicAdd(&cntB[rows[i]], 1);
}

__global__ __launch_bounds__(256) void scan_block_sums(
        const int* __restrict__ cnt, int* __restrict__ bsum, int n) {
    __shared__ int s[256];
    int i = blockIdx.x * 256 + threadIdx.x;
    s[threadIdx.x] = (i < n) ? cnt[i] : 0;
    __syncthreads();
    for (int o = 128; o > 0; o >>= 1) {
        if (threadIdx.x < o) s[threadIdx.x] += s[threadIdx.x + o];
        __syncthreads();
    }
    if (threadIdx.x == 0) bsum[blockIdx.x] = s[0];
}

__global__ __launch_bounds__(1024) void scan_top(
        int* bsum, int nb, int* __restrict__ rp, int nedge) {
    __shared__ int s[1024];
    int t = threadIdx.x;
    int v = (t < nb) ? bsum[t] : 0;
    s[t] = v;
    __syncthreads();
    for (int o = 1; o < 1024; o <<= 1) {
        int add = (t >= o) ? s[t - o] : 0;
        __syncthreads();
        s[t] += add;
        __syncthreads();
    }
    if (t < nb) bsum[t] = s[t] - v;   // exclusive
    if (t == 0) rp[N_NODE] = nedge;
}

__global__ __launch_bounds__(256) void scan_final(
        const int* __restrict__ cnt, const int* __restrict__ bsum,
        int* __restrict__ rp, int n) {
    __shared__ int s[256];
    int i = blockIdx.x * 256 + threadIdx.x;
    int v = (i < n) ? cnt[i] : 0;
    s[threadIdx.x] = v;
    __syncthreads();
    for (int o = 1; o < 256; o <<= 1) {
        int add = (threadIdx.x >= o) ? s[threadIdx.x - o] : 0;
        __syncthreads();
        s[threadIdx.x] += add;
        __syncthreads();
    }
    if (i < n) rp[i] = bsum[blockIdx.x] + s[threadIdx.x] - v;
}

__global__ __launch_bounds__(256) void edge_place_dual(
        const int* __restrict__ rows, const int* __restrict__ cols,
        const float* __restrict__ uvv, const float* __restrict__ vuv,
        const int* __restrict__ rpA, int* __restrict__ curA, int2* __restrict__ eA,
        const int* __restrict__ rpB, int* __restrict__ curB, int2* __restrict__ eB,
        int nedge) {
    int i = blockIdx.x * 256 + threadIdx.x;
    if (i >= nedge) return;
    int r = rows[i], c = cols[i];
    int pa = rpA[c] + atomicAdd(&curA[c], 1);
    eA[pa] = make_int2(r, __float_as_int(vuv[i]));
    int pb = rpB[r] + atomicAdd(&curB[r], 1);
    eB[pb] = make_int2(c, __float_as_int(uvv[i]));
}

// ---------------------------------------------------------------------------
// Gather SpMM, bf16 source, fused epilogue:
//   dst[n] = leaky(sum_e val * bf16row(src)[srcidx] + bias)   (f32 out)
// One wave per dst node; one dword (2 bf16) per lane; 4-edge unroll.
// ---------------------------------------------------------------------------
__global__ __launch_bounds__(256) void spmm_gather_act_bf16(
        const unsigned* __restrict__ src, float* __restrict__ dst,
        const int* __restrict__ rp, const int2* __restrict__ edges,
        const float* __restrict__ bias, int ndst) {
    int wid = __builtin_amdgcn_readfirstlane(
        (int)((blockIdx.x * 256u + threadIdx.x) >> 6));
    int lane = threadIdx.x & 63;
    if (wid >= ndst) return;
    float2 b = *(const float2*)(bias + lane * 2);
    int e0 = rp[wid], e1 = rp[wid + 1];
    float accx = 0.f, accy = 0.f;
    int e = e0;
    for (; e + 4 <= e1; e += 4) {
        int2 ev0 = edges[e],     ev1 = edges[e + 1];
        int2 ev2 = edges[e + 2], ev3 = edges[e + 3];
        unsigned p0 = src[(size_t)ev0.x * 64 + lane];
        unsigned p1 = src[(size_t)ev1.x * 64 + lane];
        unsigned p2 = src[(size_t)ev2.x * 64 + lane];
        unsigned p3 = src[(size_t)ev3.x * 64 + lane];
        float v0 = __int_as_float(ev0.y), v1 = __int_as_float(ev1.y);
        float v2 = __int_as_float(ev2.y), v3 = __int_as_float(ev3.y);
        accx = fmaf(v0, __uint_as_float(p0 << 16),        accx);
        accy = fmaf(v0, __uint_as_float(p0 & 0xFFFF0000u), accy);
        accx = fmaf(v1, __uint_as_float(p1 << 16),        accx);
        accy = fmaf(v1, __uint_as_float(p1 & 0xFFFF0000u), accy);
        accx = fmaf(v2, __uint_as_float(p2 << 16),        accx);
        accy = fmaf(v2, __uint_as_float(p2 & 0xFFFF0000u), accy);
        accx = fmaf(v3, __uint_as_float(p3 << 16),        accx);
        accy = fmaf(v3, __uint_as_float(p3 & 0xFFFF0000u), accy);
    }
    for (; e < e1; ++e) {
        int2 ev = edges[e];
        unsigned p = src[(size_t)ev.x * 64 + lane];
        float v = __int_as_float(ev.y);
        accx = fmaf(v, __uint_as_float(p << 16),        accx);
        accy = fmaf(v, __uint_as_float(p & 0xFFFF0000u), accy);
    }
    float ox = accx + b.x;
    float oy = accy + b.y;
    ox = (ox >= 0.f) ? ox : ALPHA * ox;
    oy = (oy >= 0.f) ? oy : ALPHA * oy;
    *(float2*)(dst + (size_t)wid * FEAT + lane * 2) = make_float2(ox, oy);
}

// ---------------------------------------------------------------------------
// Cb(bf16-packed) = A @ W  (A: Mx128 f32, W: 128x128 row-major [k][n]).
// Output row = 64 dwords; each thread writes uint4 (8 cols).
// ---------------------------------------------------------------------------
__global__ __launch_bounds__(256) void gemm_to_bf16(
        const float* __restrict__ A, const float* __restrict__ W,
        unsigned* __restrict__ Cb, int M) {
    __shared__ float Ws[FEAT * FEAT];
    {
        const float4* Wv = (const float4*)W;
        float4* Wsv = (float4*)Ws;
#pragma unroll
        for (int i = 0; i < 16; ++i)
            Wsv[threadIdx.x + i * 256] = Wv[threadIdx.x + i * 256];
    }
    __syncthreads();

    int tx = threadIdx.x & 15;
    int ty = threadIdx.x >> 4;
    long row0 = (long)blockIdx.x * 64 + ty * 4;
    if (row0 >= M) return;

    float acc[4][8] = {};
    const float* a0 = A + row0 * FEAT;

    for (int k4 = 0; k4 < FEAT; k4 += 4) {
        float4 a[4];
#pragma unroll
        for (int r = 0; r < 4; ++r)
            a[r] = *(const float4*)(a0 + (size_t)r * FEAT + k4);
#pragma unroll
        for (int kk = 0; kk < 4; ++kk) {
            float4 w0 = *(const float4*)(Ws + (k4 + kk) * FEAT + tx * 8);
            float4 w1 = *(const float4*)(Ws + (k4 + kk) * FEAT + tx * 8 + 4);
#pragma unroll
            for (int r = 0; r < 4; ++r) {
                float av = (&a[r].x)[kk];
                acc[r][0] = fmaf(av, w0.x, acc[r][0]);
                acc[r][1] = fmaf(av, w0.y, acc[r][1]);
                acc[r][2] = fmaf(av, w0.z, acc[r][2]);
                acc[r][3] = fmaf(av, w0.w, acc[r][3]);
                acc[r][4] = fmaf(av, w1.x, acc[r][4]);
                acc[r][5] = fmaf(av, w1.y, acc[r][5]);
                acc[r][6] = fmaf(av, w1.z, acc[r][6]);
                acc[r][7] = fmaf(av, w1.w, acc[r][7]);
            }
        }
    }

#pragma unroll
    for (int r = 0; r < 4; ++r) {
        uint4 o;
        o.x = bf16pk(acc[r][0], acc[r][1]);
        o.y = bf16pk(acc[r][2], acc[r][3]);
        o.z = bf16pk(acc[r][4], acc[r][5]);
        o.w = bf16pk(acc[r][6], acc[r][7]);
        *(uint4*)(Cb + (row0 + r) * 64 + tx * 4) = o;
    }
}

// ---------------------------------------------------------------------------
// C = relu(A @ W[0:128] + F @ W[128:256] + bias), W: 256x128.
// ---------------------------------------------------------------------------
__global__ __launch_bounds__(256) void gemm_concat_relu(
        const float* __restrict__ A, const float* __restrict__ F,
        const float* __restrict__ W, const float* __restrict__ bias,
        float* __restrict__ C, int M) {
    __shared__ float Ws[FEAT * FEAT];
    int tx = threadIdx.x & 15;
    int ty = threadIdx.x >> 4;
    long row0 = (long)blockIdx.x * 64 + ty * 4;
    float acc[4][8] = {};

    for (int half = 0; half < 2; ++half) {
        __syncthreads();
        {
            const float4* Wv = (const float4*)(W + (size_t)half * FEAT * FEAT);
            float4* Wsv = (float4*)Ws;
#pragma unroll
            for (int i = 0; i < 16; ++i)
                Wsv[threadIdx.x + i * 256] = Wv[threadIdx.x + i * 256];
        }
        __syncthreads();

        const float* base = (half == 0 ? A : F);
        const float* a0 = base + row0 * FEAT;
        for (int k4 = 0; k4 < FEAT; k4 += 4) {
            float4 a[4];
#pragma unroll
            for (int r = 0; r < 4; ++r)
                a[r] = *(const float4*)(a0 + (size_t)r * FEAT + k4);
#pragma unroll
            for (int kk = 0; kk < 4; ++kk) {
                float4 w0 = *(const float4*)(Ws + (k4 + kk) * FEAT + tx * 8);
                float4 w1 = *(const float4*)(Ws + (k4 + kk) * FEAT + tx * 8 + 4);
#pragma unroll
                for (int r = 0; r < 4; ++r) {
                    float av = (&a[r].x)[kk];
                    acc[r][0] = fmaf(av, w0.x, acc[r][0]);
                    acc[r][1] = fmaf(av, w0.y, acc[r][1]);
                    acc[r][2] = fmaf(av, w0.z, acc[r][2]);
                    acc[r][3] = fmaf(av, w0.w, acc[r][3]);
                    acc[r][4] = fmaf(av, w1.x, acc[r][4]);
                    acc[r][5] = fmaf(av, w1.y, acc[r][5]);
                    acc[r][6] = fmaf(av, w1.z, acc[r][6]);
                    acc[r][7] = fmaf(av, w1.w, acc[r][7]);
                }
            }
        }
    }

    float b0[8];
#pragma unroll
    for (int i = 0; i < 8; ++i) b0[i] = bias[tx * 8 + i];
#pragma unroll
    for (int r = 0; r < 4; ++r) {
        float o[8];
#pragma unroll
        for (int i = 0; i < 8; ++i) {
            float v = acc[r][i] + b0[i];
            o[i] = (v >= 0.f) ? v : 0.f;
        }
        float* cp = C + (row0 + r) * FEAT + tx * 8;
        *(float4*)cp       = make_float4(o[0], o[1], o[2], o[3]);
        *(float4*)(cp + 4) = make_float4(o[4], o[5], o[6], o[7]);
    }
}

// ---------------------------------------------------------------------------
extern "C" void kernel_launch(void* const* d_in, const int* in_sizes, int n_in,
                              void* d_out, int out_size, void* d_ws, size_t ws_size,
                              hipStream_t stream) {
    const float* ufea    = (const float*)d_in[0];
    const float* vfea    = (const float*)d_in[1];
    const int*   uv_rows = (const int*)d_in[2];
    const int*   uv_cols = (const int*)d_in[3];
    const float* uv_vals = (const float*)d_in[4];
    const float* vu_vals = (const float*)d_in[5];
    const float* W1 = (const float*)d_in[6];
    const float* b1 = (const float*)d_in[7];
    const float* W2 = (const float*)d_in[8];
    const float* b2 = (const float*)d_in[9];
    const float* W3 = (const float*)d_in[10];
    const float* b3 = (const float*)d_in[11];
    const float* W4 = (const float*)d_in[12];
    const float* b4 = (const float*)d_in[13];
    const float* Wu = (const float*)d_in[14];
    const float* bu = (const float*)d_in[15];
    const float* Wi = (const float*)d_in[16];
    const float* bi = (const float*)d_in[17];

    float* out_user = (float*)d_out;
    float* out_item = out_user + (size_t)N_NODE * FEAT;

    int nedge = in_sizes[2];
    size_t nfe = (size_t)N_NODE * FEAT;        // 25.6M floats

    unsigned* Gb = (unsigned*)d_ws;            // bf16-packed G, 51.2MB (nfe/2 dwords)
    float* B = (float*)(Gb + nfe / 2);         // f32 feature buf
    float* C = B + nfe;
    int* rpA  = (int*)(C + nfe);               // N_NODE+1 (padded)
    int* rpB  = rpA + (N_NODE + 64);
    int* cnt  = rpB + (N_NODE + 64);           // 2*N_NODE: [cntA | cntB]
    int* cntA = cnt;
    int* cntB = cnt + N_NODE;
    int* bsum = cntB + N_NODE;                 // <=1024
    int2* eA  = (int2*)(bsum + 1024);          // AoS {src, val_bits}
    int2* eB  = eA + nedge;

    int eb = (nedge + 255) / 256;
    int nb = (N_NODE + 255) / 256;             // 782
    dim3 b256(256);
    dim3 ggrid((unsigned)(N_NODE / 64));       // 3125
    dim3 sgrid((unsigned)(N_NODE / 4));        // 50000: wave per dst node

    // ---- dual CSR build ----
    hipMemsetAsync(cnt, 0, 2u * N_NODE * sizeof(int), stream);
    edge_hist_dual<<<eb, b256, 0, stream>>>(uv_rows, uv_cols, cntA, cntB, nedge);
    scan_block_sums<<<nb, b256, 0, stream>>>(cntA, bsum, N_NODE);
    scan_top<<<1, 1024, 0, stream>>>(bsum, nb, rpA, nedge);
    scan_final<<<nb, b256, 0, stream>>>(cntA, bsum, rpA, N_NODE);
    scan_block_sums<<<nb, b256, 0, stream>>>(cntB, bsum, N_NODE);
    scan_top<<<1, 1024, 0, stream>>>(bsum, nb, rpB, nedge);
    scan_final<<<nb, b256, 0, stream>>>(cntB, bsum, rpB, N_NODE);
    hipMemsetAsync(cnt, 0, 2u * N_NODE * sizeof(int), stream);
    edge_place_dual<<<eb, b256, 0, stream>>>(uv_rows, uv_cols, uv_vals, vu_vals,
                                             rpA, cntA, eA, rpB, cntB, eB, nedge);

    // gc1: Gb = bf16(ufea@W1);  T1 = leaky(gatherA(Gb)+b1) -> B
    gemm_to_bf16<<<ggrid, b256, 0, stream>>>(ufea, W1, Gb, N_NODE);
    spmm_gather_act_bf16<<<sgrid, b256, 0, stream>>>(Gb, B, rpA, eA, b1, N_NODE);

    // gc2: Gb = bf16(vfea@W2);  T2 = leaky(gatherB(Gb)+b2) -> C
    gemm_to_bf16<<<ggrid, b256, 0, stream>>>(vfea, W2, Gb, N_NODE);
    spmm_gather_act_bf16<<<sgrid, b256, 0, stream>>>(Gb, C, rpB, eB, b2, N_NODE);

    // gc3: Gb = bf16(T1@W3);    T3 = leaky(gatherB(Gb)+b3) -> B (T1 dead)
    gemm_to_bf16<<<ggrid, b256, 0, stream>>>(B, W3, Gb, N_NODE);
    spmm_gather_act_bf16<<<sgrid, b256, 0, stream>>>(Gb, B, rpB, eB, b3, N_NODE);

    // gc4: Gb = bf16(T2@W4);    T4 = leaky(gatherA(Gb)+b4) -> C (T2 dead)
    gemm_to_bf16<<<ggrid, b256, 0, stream>>>(C, W4, Gb, N_NODE);
    spmm_gather_act_bf16<<<sgrid, b256, 0, stream>>>(Gb, C, rpA, eA, b4, N_NODE);

    // finals
    gemm_concat_relu<<<ggrid, b256, 0, stream>>>(B, ufea, Wu, bu, out_user, N_NODE);
    gemm_concat_relu<<<ggrid, b256, 0, stream>>>(C, vfea, Wi, bi, out_item, N_NODE);
}